// Round 1
// baseline (290.528 us; speedup 1.0000x reference)
//
#include <hip/hip_runtime.h>

#define BATCH  2
#define DM     96
#define DI     192
#define NSTATE 16
#define RRANK  6
#define KDIR   6
#define L      4096
#define ROWW   40   // padded x_dbl row: [0..5]=dts, [6..7]=0, [8..23]=B, [24..39]=C
#define LC     64
#define NCHUNK (L / LC)
#define HALO   64

// spatial index (d,h,w flattened) for direction k at sequence position l
__device__ __forceinline__ int map_s(int k, int l) {
  int lp = (k & 1) ? (L - 1 - l) : l;
  int kb = k >> 1;
  if (kb == 0) return lp;                       // [d][h][w]
  int a = lp >> 8, b = (lp >> 4) & 15, c = lp & 15;
  if (kb == 1) return (b << 8) | (a << 4) | c;  // seq [h][d][w] -> spatial
  return (b << 8) | (c << 4) | a;               // seq [w][d][h] -> spatial
}

// ---------------- xz = x @ W_in^T -------------------------------------------
// block: 64 positions x 96-oc slice. LDS f4 tiles, 96 FMA per 10 ds_read_b128.
#define XZ_SP 25
__global__ __launch_bounds__(256) void k_xz(const float* __restrict__ x,
    const float* __restrict__ W_in, float* __restrict__ xe_c, float* __restrict__ z) {
  __shared__ float4 xt[64 * XZ_SP];
  __shared__ float4 wt[96 * XZ_SP];
  int blk = blockIdx.x;
  int slice = blk & 3, tile = (blk >> 2) & 63, b = blk >> 8;
  int s0 = tile << 6, oc0 = slice * 96;
  const float4* xg = (const float4*)(x + ((size_t)(b * L + s0)) * DM);
  for (int i = threadIdx.x; i < 64 * 24; i += 256) {
    int p = i / 24, q = i - p * 24;
    xt[p * XZ_SP + q] = xg[i];
  }
  const float4* wg = (const float4*)(W_in + (size_t)oc0 * DM);
  for (int i = threadIdx.x; i < 96 * 24; i += 256) {
    int r = i / 24, q = i - r * 24;
    wt[r * XZ_SP + q] = wg[i];
  }
  __syncthreads();
  int og = threadIdx.x & 15, pg = threadIdx.x >> 4;
  float acc[4][6];
  #pragma unroll
  for (int j = 0; j < 4; ++j)
    #pragma unroll
    for (int m = 0; m < 6; ++m) acc[j][m] = 0.f;
  for (int q = 0; q < 24; ++q) {
    float4 xv[4], wv[6];
    #pragma unroll
    for (int j = 0; j < 4; ++j) xv[j] = xt[(pg * 4 + j) * XZ_SP + q];
    #pragma unroll
    for (int m = 0; m < 6; ++m) wv[m] = wt[(og * 6 + m) * XZ_SP + q];
    #pragma unroll
    for (int j = 0; j < 4; ++j)
      #pragma unroll
      for (int m = 0; m < 6; ++m) {
        acc[j][m] = fmaf(xv[j].x, wv[m].x, acc[j][m]);
        acc[j][m] = fmaf(xv[j].y, wv[m].y, acc[j][m]);
        acc[j][m] = fmaf(xv[j].z, wv[m].z, acc[j][m]);
        acc[j][m] = fmaf(xv[j].w, wv[m].w, acc[j][m]);
      }
  }
  if (slice < 2) {
    #pragma unroll
    for (int m = 0; m < 6; ++m) {
      int oc = oc0 + og * 6 + m;
      float4 v = make_float4(acc[0][m], acc[1][m], acc[2][m], acc[3][m]);
      *(float4*)(xe_c + ((size_t)(b * DI + oc)) * L + s0 + pg * 4) = v;
    }
  } else {
    #pragma unroll
    for (int j = 0; j < 4; ++j)
      #pragma unroll
      for (int m = 0; m < 6; ++m) {
        int zc = (oc0 - DI) + og * 6 + m;
        z[((size_t)(b * L + s0 + pg * 4 + j)) * DI + zc] = acc[j][m];
      }
  }
}

// ---------------- depthwise conv3d + SiLU, channel-major out ----------------
__global__ __launch_bounds__(256) void k_conv(const float* __restrict__ xe_c,
    const float* __restrict__ conv_w, const float* __restrict__ conv_b,
    float* __restrict__ xc_c) {
  __shared__ float ch[L];
  int b = blockIdx.x / DI, c = blockIdx.x % DI;
  const float4* src = (const float4*)(xe_c + ((size_t)(b * DI + c)) * L);
  for (int i = threadIdx.x; i < L / 4; i += 256) ((float4*)ch)[i] = src[i];
  float w[27];
  #pragma unroll
  for (int j = 0; j < 27; ++j) w[j] = conv_w[c * 27 + j];
  float bias = conv_b[c];
  __syncthreads();
  float* dst = xc_c + ((size_t)(b * DI + c)) * L;
  for (int i = threadIdx.x; i < L; i += 256) {
    int d = i >> 8, h = (i >> 4) & 15, iw = i & 15;
    float acc = bias;
    #pragma unroll
    for (int kd = 0; kd < 3; ++kd) {
      int dd = d + kd - 1;
      #pragma unroll
      for (int kh = 0; kh < 3; ++kh) {
        int hh = h + kh - 1;
        #pragma unroll
        for (int kw = 0; kw < 3; ++kw) {
          int wwp = iw + kw - 1;
          if ((unsigned)dd < 16u && (unsigned)hh < 16u && (unsigned)wwp < 16u)
            acc = fmaf(ch[(dd << 8) | (hh << 4) | wwp], w[kd * 9 + kh * 3 + kw], acc);
        }
      }
    }
    dst[i] = acc / (1.f + __expf(-acc));
  }
}

// ---------------- transpose [b][c][s] -> [b][s][c] --------------------------
__global__ __launch_bounds__(256) void k_tr(const float* __restrict__ src,
                                            float* __restrict__ dst) {
  __shared__ float t[32][33];
  int blk = blockIdx.x;
  int st = blk & 127, ct = (blk >> 7) % 6, b = blk / (128 * 6);
  int s0 = st << 5, c0 = ct << 5;
  int i = threadIdx.x >> 5, j = threadIdx.x & 31;
  #pragma unroll
  for (int k2 = 0; k2 < 4; ++k2)
    t[i + 8 * k2][j] = src[((size_t)(b * DI + c0 + i + 8 * k2)) * L + s0 + j];
  __syncthreads();
  #pragma unroll
  for (int k2 = 0; k2 < 4; ++k2)
    dst[((size_t)(b * L + s0 + i + 8 * k2)) * DI + c0 + j] = t[j][i + 8 * k2];
}

// ---------------- x_dbl = x_proj_w[k] @ xs rows -----------------------------
#define PJ_SP 49
__global__ __launch_bounds__(256) void k_proj(const float* __restrict__ xc_t,
    const float* __restrict__ xpw, float* __restrict__ xdbl) {
  __shared__ float4 wp[38 * PJ_SP];
  __shared__ float4 xr[32 * PJ_SP];
  __shared__ float  xd[32][ROWW];
  int blk = blockIdx.x;
  int lt = blk & 127, bk = blk >> 7;
  int k = bk % KDIR, b = bk / KDIR;
  int l0 = lt << 5;
  const float4* wsrc = (const float4*)(xpw + (size_t)k * 38 * DI);
  for (int i = threadIdx.x; i < 38 * 48; i += 256) {
    int r = i / 48, q = i - r * 48;
    wp[r * PJ_SP + q] = wsrc[i];
  }
  const float4* xsrc = (const float4*)xc_t;
  for (int i = threadIdx.x; i < 32 * 48; i += 256) {
    int lr = i / 48, q = i - lr * 48;
    int s = map_s(k, l0 + lr);
    xr[lr * PJ_SP + q] = xsrc[((size_t)(b * L + s)) * 48 + q];
  }
  if (threadIdx.x < 32) { xd[threadIdx.x][6] = 0.f; xd[threadIdx.x][7] = 0.f; }
  __syncthreads();
  int lr = threadIdx.x & 31, dg = threadIdx.x >> 5;
  float acc[5] = {0.f, 0.f, 0.f, 0.f, 0.f};
  for (int q = 0; q < 48; ++q) {
    float4 xv = xr[lr * PJ_SP + q];
    #pragma unroll
    for (int j = 0; j < 5; ++j) {
      int dd = dg * 5 + j;
      if (dd < 38) {
        float4 wv = wp[dd * PJ_SP + q];
        acc[j] = fmaf(xv.x, wv.x, acc[j]);
        acc[j] = fmaf(xv.y, wv.y, acc[j]);
        acc[j] = fmaf(xv.z, wv.z, acc[j]);
        acc[j] = fmaf(xv.w, wv.w, acc[j]);
      }
    }
  }
  #pragma unroll
  for (int j = 0; j < 5; ++j) {
    int dd = dg * 5 + j;
    if (dd < 38) xd[lr][dd < 6 ? dd : dd + 2] = acc[j];
  }
  __syncthreads();
  float4* xo = (float4*)(xdbl + (size_t)bk * L * ROWW + (size_t)l0 * ROWW);
  for (int i = threadIdx.x; i < 32 * 10; i += 256) {
    int lr2 = i / 10, q = i - lr2 * 10;
    xo[lr2 * 10 + q] = ((float4*)&xd[lr2][0])[q];
  }
}

// ---------------- chunked selective scan ------------------------------------
// 2-way state split: thread t -> channel c = t>>1, states half*8..half*8+7.
// 384 threads = 6 waves/block (vs 3): doubles latency-hiding TLP, halves the
// per-step serial h/y work. y combined across the lane pair with shfl_xor(1).
// u gather pipelined 3 steps ahead (was 1) to cover L2/L3 latency.
__global__ void __launch_bounds__(384) k_scan(const float* __restrict__ xc_t,
    const float* __restrict__ xdbl, const float* __restrict__ dtw,
    const float* __restrict__ dtb, const float* __restrict__ A_logs,
    const float* __restrict__ Ds, float* __restrict__ y_sum) {
  __shared__ float4 rows[128 * 10];   // up to 128 rows x 40 floats
  int blk = blockIdx.x;
  int chk = blk & (NCHUNK - 1);
  int bk = blk >> 6;                  // NCHUNK == 64
  int k = bk % KDIR, b = bk / KDIR;
  int t = threadIdx.x;
  int c = t >> 1;                     // channel 0..191
  int half = t & 1;                   // state group: 0 -> n=0..7, 1 -> n=8..15
  int lo = chk * LC;
  int ls = lo - HALO; if (ls < 0) ls = 0;
  int e = lo + LC;
  int nr = e - ls;
  const float4* rsrc = (const float4*)(xdbl + (size_t)bk * L * ROWW) + (size_t)ls * 10;
  for (int i = t; i < nr * 10; i += 384) rows[i] = rsrc[i];
  float wdt[RRANK];
  #pragma unroll
  for (int r = 0; r < RRANK; ++r) wdt[r] = dtw[(k * DI + c) * RRANK + r];
  float bias = dtb[k * DI + c];
  float Dv = Ds[k * DI + c];
  const float* alog = A_logs + (size_t)(k * DI + c) * NSTATE + half * 8;
  bool fast = true;
  #pragma unroll
  for (int j = 0; j < 8; ++j)
    fast = fast && (fabsf(__expf(alog[j]) - (float)(half * 8 + j + 1)) < 1e-4f);
  float h[8];
  #pragma unroll
  for (int j = 0; j < 8; ++j) h[j] = 0.f;
  const float* ub = xc_t + (size_t)b * L * DI + c;
  float* yb = y_sum + (size_t)b * L * DI + c;

  // u-prefetch pipeline (distance 3) -- independent of LDS, issue pre-barrier
  int sA = map_s(k, ls);
  float uA = ub[(size_t)sA * DI];
  int sB = (ls + 1 < e) ? map_s(k, ls + 1) : sA;
  float uB = ub[(size_t)sB * DI];
  int sC = (ls + 2 < e) ? map_s(k, ls + 2) : sA;
  float uC = ub[(size_t)sC * DI];
  __syncthreads();

  if (fast) {  // A[n] == -(n+1): dA[n] = e1^(n+1), log-depth powers
    for (int l = ls; l < e; ++l) {
      // prefetch u for l+3
      int l3 = l + 3;
      int sD = (l3 < e) ? map_s(k, l3) : sA;
      float uD = ub[(size_t)sD * DI];
      const float4* rp = &rows[(l - ls) * 10];
      float4 r0 = rp[0], r1 = rp[1];
      float dtv = bias;
      dtv = fmaf(r0.x, wdt[0], dtv); dtv = fmaf(r0.y, wdt[1], dtv);
      dtv = fmaf(r0.z, wdt[2], dtv); dtv = fmaf(r0.w, wdt[3], dtv);
      dtv = fmaf(r1.x, wdt[4], dtv); dtv = fmaf(r1.y, wdt[5], dtv);
      float sp = fmaxf(dtv, 0.f) + __logf(1.f + __expf(-fabsf(dtv)));
      float e1 = __expf(-sp);
      float dtu = sp * uA;
      float p2 = e1 * e1, p3 = p2 * e1, p4 = p2 * p2;
      float pw0 = e1, pw1 = p2, pw2 = p3, pw3 = p4;
      float pw4 = p4 * e1, pw5 = p4 * p2, pw6 = p4 * p3, pw7 = p4 * p4;
      float sc = half ? pw7 : 1.f;    // half 1: states 8..15 -> e1^9..e1^16
      float4 B0 = rp[2 + half * 2], B1 = rp[3 + half * 2];
      float4 C0 = rp[6 + half * 2], C1 = rp[7 + half * 2];
      float y = 0.f;
      h[0] = fmaf(pw0 * sc, h[0], dtu * B0.x); y = fmaf(h[0], C0.x, y);
      h[1] = fmaf(pw1 * sc, h[1], dtu * B0.y); y = fmaf(h[1], C0.y, y);
      h[2] = fmaf(pw2 * sc, h[2], dtu * B0.z); y = fmaf(h[2], C0.z, y);
      h[3] = fmaf(pw3 * sc, h[3], dtu * B0.w); y = fmaf(h[3], C0.w, y);
      h[4] = fmaf(pw4 * sc, h[4], dtu * B1.x); y = fmaf(h[4], C1.x, y);
      h[5] = fmaf(pw5 * sc, h[5], dtu * B1.y); y = fmaf(h[5], C1.y, y);
      h[6] = fmaf(pw6 * sc, h[6], dtu * B1.z); y = fmaf(h[6], C1.z, y);
      h[7] = fmaf(pw7 * sc, h[7], dtu * B1.w); y = fmaf(h[7], C1.w, y);
      float y2 = y + __shfl_xor(y, 1, 64);
      if (l >= lo && half == 0)
        atomicAdd(yb + (size_t)sA * DI, fmaf(Dv, uA, y2));
      sA = sB; uA = uB; sB = sC; uB = uC; sC = sD; uC = uD;
    }
  } else {     // generic fallback (split states, direct loads)
    float al[8];
    #pragma unroll
    for (int j = 0; j < 8; ++j) al[j] = alog[j];
    for (int l = ls; l < e; ++l) {
      const float4* rp = &rows[(l - ls) * 10];
      const float* rf = (const float*)rp;
      float dtv = bias;
      #pragma unroll
      for (int r = 0; r < RRANK; ++r) dtv = fmaf(rf[r], wdt[r], dtv);
      float sp = fmaxf(dtv, 0.f) + __logf(1.f + __expf(-fabsf(dtv)));
      int s = map_s(k, l);
      float u = ub[(size_t)s * DI];
      float dtu = sp * u;
      float y = 0.f;
      #pragma unroll
      for (int j = 0; j < 8; ++j) {
        int n = half * 8 + j;
        float dA = __expf(sp * (-__expf(al[j])));
        h[j] = fmaf(dA, h[j], dtu * rf[8 + n]);
        y = fmaf(h[j], rf[24 + n], y);
      }
      float y2 = y + __shfl_xor(y, 1, 64);
      if (l >= lo && half == 0)
        atomicAdd(yb + (size_t)s * DI, fmaf(Dv, u, y2));
    }
  }
}

// ---------------- LN -> gate -> W_out ---------------------------------------
#define FN_SP 49
__global__ __launch_bounds__(256) void k_final(const float* __restrict__ y_sum,
    const float* __restrict__ zb, const float* __restrict__ lnw,
    const float* __restrict__ lnb, const float* __restrict__ W_out,
    float* __restrict__ out) {
  __shared__ float4 ys4[16 * FN_SP];
  float* ys = (float*)ys4;
  int p0 = blockIdx.x << 4;
  int t = threadIdx.x;
  const float4* yg = (const float4*)(y_sum + (size_t)p0 * DI);
  for (int i = t; i < 16 * 48; i += 256) {
    int r = i / 48, q = i - r * 48;
    ys4[r * FN_SP + q] = yg[i];
  }
  __syncthreads();
  {
    int r = t >> 4, lg = t & 15;
    float v[12], s1 = 0.f, s2 = 0.f;
    #pragma unroll
    for (int j2 = 0; j2 < 12; ++j2) {
      float vv = ys[r * (FN_SP * 4) + lg + 16 * j2];
      v[j2] = vv; s1 += vv; s2 += vv * vv;
    }
    #pragma unroll
    for (int m = 1; m < 16; m <<= 1) {
      s1 += __shfl_xor(s1, m, 64);
      s2 += __shfl_xor(s2, m, 64);
    }
    float mu = s1 * (1.f / DI);
    float var = s2 * (1.f / DI) - mu * mu;
    float rs = rsqrtf(var + 1e-5f);
    #pragma unroll
    for (int j2 = 0; j2 < 12; ++j2) {
      int cc = lg + 16 * j2;
      float g = zb[(size_t)(p0 + r) * DI + cc];
      float yl = (v[j2] - mu) * rs * lnw[cc] + lnb[cc];
      ys[r * (FN_SP * 4) + cc] = yl * (g / (1.f + __expf(-g)));
    }
  }
  __syncthreads();
  int oc = t % 96, pg = t / 96;       // pg in {0,1,2}; pg==2 idle
  if (pg < 2) {
    const float4* wg4 = (const float4*)W_out;
    float acc[8];
    #pragma unroll
    for (int j = 0; j < 8; ++j) acc[j] = 0.f;
    for (int q = 0; q < 48; ++q) {
      float4 wv = wg4[oc * 48 + q];
      #pragma unroll
      for (int pp = 0; pp < 8; ++pp) {
        float4 yv = ys4[(pg * 8 + pp) * FN_SP + q];
        acc[pp] = fmaf(yv.x, wv.x, acc[pp]);
        acc[pp] = fmaf(yv.y, wv.y, acc[pp]);
        acc[pp] = fmaf(yv.z, wv.z, acc[pp]);
        acc[pp] = fmaf(yv.w, wv.w, acc[pp]);
      }
    }
    #pragma unroll
    for (int pp = 0; pp < 8; ++pp)
      out[(size_t)(p0 + pg * 8 + pp) * DM + oc] = acc[pp];
  }
}

extern "C" void kernel_launch(void* const* d_in, const int* in_sizes, int n_in,
                              void* d_out, int out_size, void* d_ws, size_t ws_size,
                              hipStream_t stream) {
  const float* x        = (const float*)d_in[0];
  const float* W_in     = (const float*)d_in[1];
  const float* conv_w   = (const float*)d_in[2];
  const float* conv_b   = (const float*)d_in[3];
  const float* x_proj_w = (const float*)d_in[4];
  const float* dt_proj_w= (const float*)d_in[5];
  const float* dt_proj_b= (const float*)d_in[6];
  const float* A_logs   = (const float*)d_in[7];
  const float* Ds       = (const float*)d_in[8];
  const float* ln_w     = (const float*)d_in[9];
  const float* ln_b     = (const float*)d_in[10];
  const float* W_out    = (const float*)d_in[11];
  float* out = (float*)d_out;

  float* ws   = (float*)d_ws;
  float* regA = ws;                                    // xe_c, later ysum (B*DI*L)
  float* zb   = regA + (size_t)BATCH * DI * L;
  float* xc_c = zb   + (size_t)BATCH * L * DI;
  float* xc_t = xc_c + (size_t)BATCH * L * DI;
  float* xdbl = xc_t + (size_t)BATCH * L * DI;         // B*K*L*ROWW

  k_xz  <<<BATCH * 64 * 4, 256, 0, stream>>>(x, W_in, regA, zb);
  k_conv<<<BATCH * DI,     256, 0, stream>>>(regA, conv_w, conv_b, xc_c);
  k_tr  <<<BATCH * 6 * 128, 256, 0, stream>>>(xc_c, xc_t);
  hipMemsetAsync(regA, 0, (size_t)BATCH * L * DI * sizeof(float), stream);  // ysum
  k_proj<<<BATCH * KDIR * 128, 256, 0, stream>>>(xc_t, x_proj_w, xdbl);
  k_scan<<<BATCH * KDIR * NCHUNK, 384, 0, stream>>>(xc_t, xdbl, dt_proj_w, dt_proj_b,
                                                    A_logs, Ds, regA);
  k_final<<<BATCH * L / 16, 256, 0, stream>>>(regA, zb, ln_w, ln_b, W_out, out);
}

// Round 2
// 249.676 us; speedup vs baseline: 1.1636x; 1.1636x over previous
//
#include <hip/hip_runtime.h>

#define BATCH  2
#define DM     96
#define DI     192
#define NSTATE 16
#define RRANK  6
#define KDIR   6
#define L      4096
#define ROWW   40   // padded x_dbl row: [0..5]=dts, [6..7]=0, [8..23]=B, [24..39]=C
#define LC     64
#define NCHUNK (L / LC)
#define HALO   64

// spatial index (d,h,w flattened) for direction k at sequence position l
__device__ __forceinline__ int map_s(int k, int l) {
  int lp = (k & 1) ? (L - 1 - l) : l;
  int kb = k >> 1;
  if (kb == 0) return lp;                       // [d][h][w]
  int a = lp >> 8, b = (lp >> 4) & 15, c = lp & 15;
  if (kb == 1) return (b << 8) | (a << 4) | c;  // seq [h][d][w] -> spatial
  return (b << 8) | (c << 4) | a;               // seq [w][d][h] -> spatial
}

// ---------------- xz = x @ W_in^T -------------------------------------------
// block: 64 positions x 96-oc slice. LDS f4 tiles, 96 FMA per 10 ds_read_b128.
#define XZ_SP 25
__global__ __launch_bounds__(256) void k_xz(const float* __restrict__ x,
    const float* __restrict__ W_in, float* __restrict__ xe_c, float* __restrict__ z) {
  __shared__ float4 xt[64 * XZ_SP];
  __shared__ float4 wt[96 * XZ_SP];
  int blk = blockIdx.x;
  int slice = blk & 3, tile = (blk >> 2) & 63, b = blk >> 8;
  int s0 = tile << 6, oc0 = slice * 96;
  const float4* xg = (const float4*)(x + ((size_t)(b * L + s0)) * DM);
  for (int i = threadIdx.x; i < 64 * 24; i += 256) {
    int p = i / 24, q = i - p * 24;
    xt[p * XZ_SP + q] = xg[i];
  }
  const float4* wg = (const float4*)(W_in + (size_t)oc0 * DM);
  for (int i = threadIdx.x; i < 96 * 24; i += 256) {
    int r = i / 24, q = i - r * 24;
    wt[r * XZ_SP + q] = wg[i];
  }
  __syncthreads();
  int og = threadIdx.x & 15, pg = threadIdx.x >> 4;
  float acc[4][6];
  #pragma unroll
  for (int j = 0; j < 4; ++j)
    #pragma unroll
    for (int m = 0; m < 6; ++m) acc[j][m] = 0.f;
  for (int q = 0; q < 24; ++q) {
    float4 xv[4], wv[6];
    #pragma unroll
    for (int j = 0; j < 4; ++j) xv[j] = xt[(pg * 4 + j) * XZ_SP + q];
    #pragma unroll
    for (int m = 0; m < 6; ++m) wv[m] = wt[(og * 6 + m) * XZ_SP + q];
    #pragma unroll
    for (int j = 0; j < 4; ++j)
      #pragma unroll
      for (int m = 0; m < 6; ++m) {
        acc[j][m] = fmaf(xv[j].x, wv[m].x, acc[j][m]);
        acc[j][m] = fmaf(xv[j].y, wv[m].y, acc[j][m]);
        acc[j][m] = fmaf(xv[j].z, wv[m].z, acc[j][m]);
        acc[j][m] = fmaf(xv[j].w, wv[m].w, acc[j][m]);
      }
  }
  if (slice < 2) {
    #pragma unroll
    for (int m = 0; m < 6; ++m) {
      int oc = oc0 + og * 6 + m;
      float4 v = make_float4(acc[0][m], acc[1][m], acc[2][m], acc[3][m]);
      *(float4*)(xe_c + ((size_t)(b * DI + oc)) * L + s0 + pg * 4) = v;
    }
  } else {
    #pragma unroll
    for (int j = 0; j < 4; ++j)
      #pragma unroll
      for (int m = 0; m < 6; ++m) {
        int zc = (oc0 - DI) + og * 6 + m;
        z[((size_t)(b * L + s0 + pg * 4 + j)) * DI + zc] = acc[j][m];
      }
  }
}

// ---------------- depthwise conv3d + SiLU, channel-major out ----------------
__global__ __launch_bounds__(256) void k_conv(const float* __restrict__ xe_c,
    const float* __restrict__ conv_w, const float* __restrict__ conv_b,
    float* __restrict__ xc_c) {
  __shared__ float ch[L];
  int b = blockIdx.x / DI, c = blockIdx.x % DI;
  const float4* src = (const float4*)(xe_c + ((size_t)(b * DI + c)) * L);
  for (int i = threadIdx.x; i < L / 4; i += 256) ((float4*)ch)[i] = src[i];
  float w[27];
  #pragma unroll
  for (int j = 0; j < 27; ++j) w[j] = conv_w[c * 27 + j];
  float bias = conv_b[c];
  __syncthreads();
  float* dst = xc_c + ((size_t)(b * DI + c)) * L;
  for (int i = threadIdx.x; i < L; i += 256) {
    int d = i >> 8, h = (i >> 4) & 15, iw = i & 15;
    float acc = bias;
    #pragma unroll
    for (int kd = 0; kd < 3; ++kd) {
      int dd = d + kd - 1;
      #pragma unroll
      for (int kh = 0; kh < 3; ++kh) {
        int hh = h + kh - 1;
        #pragma unroll
        for (int kw = 0; kw < 3; ++kw) {
          int wwp = iw + kw - 1;
          if ((unsigned)dd < 16u && (unsigned)hh < 16u && (unsigned)wwp < 16u)
            acc = fmaf(ch[(dd << 8) | (hh << 4) | wwp], w[kd * 9 + kh * 3 + kw], acc);
        }
      }
    }
    dst[i] = acc / (1.f + __expf(-acc));
  }
}

// ---------------- transpose [b][c][s] -> [b][s][c] --------------------------
__global__ __launch_bounds__(256) void k_tr(const float* __restrict__ src,
                                            float* __restrict__ dst) {
  __shared__ float t[32][33];
  int blk = blockIdx.x;
  int st = blk & 127, ct = (blk >> 7) % 6, b = blk / (128 * 6);
  int s0 = st << 5, c0 = ct << 5;
  int i = threadIdx.x >> 5, j = threadIdx.x & 31;
  #pragma unroll
  for (int k2 = 0; k2 < 4; ++k2)
    t[i + 8 * k2][j] = src[((size_t)(b * DI + c0 + i + 8 * k2)) * L + s0 + j];
  __syncthreads();
  #pragma unroll
  for (int k2 = 0; k2 < 4; ++k2)
    dst[((size_t)(b * L + s0 + i + 8 * k2)) * DI + c0 + j] = t[j][i + 8 * k2];
}

// ---------------- x_dbl = x_proj_w[k] @ xs rows -----------------------------
#define PJ_SP 49
__global__ __launch_bounds__(256) void k_proj(const float* __restrict__ xc_t,
    const float* __restrict__ xpw, float* __restrict__ xdbl) {
  __shared__ float4 wp[38 * PJ_SP];
  __shared__ float4 xr[32 * PJ_SP];
  __shared__ float  xd[32][ROWW];
  int blk = blockIdx.x;
  int lt = blk & 127, bk = blk >> 7;
  int k = bk % KDIR, b = bk / KDIR;
  int l0 = lt << 5;
  const float4* wsrc = (const float4*)(xpw + (size_t)k * 38 * DI);
  for (int i = threadIdx.x; i < 38 * 48; i += 256) {
    int r = i / 48, q = i - r * 48;
    wp[r * PJ_SP + q] = wsrc[i];
  }
  const float4* xsrc = (const float4*)xc_t;
  for (int i = threadIdx.x; i < 32 * 48; i += 256) {
    int lr = i / 48, q = i - lr * 48;
    int s = map_s(k, l0 + lr);
    xr[lr * PJ_SP + q] = xsrc[((size_t)(b * L + s)) * 48 + q];
  }
  if (threadIdx.x < 32) { xd[threadIdx.x][6] = 0.f; xd[threadIdx.x][7] = 0.f; }
  __syncthreads();
  int lr = threadIdx.x & 31, dg = threadIdx.x >> 5;
  float acc[5] = {0.f, 0.f, 0.f, 0.f, 0.f};
  for (int q = 0; q < 48; ++q) {
    float4 xv = xr[lr * PJ_SP + q];
    #pragma unroll
    for (int j = 0; j < 5; ++j) {
      int dd = dg * 5 + j;
      if (dd < 38) {
        float4 wv = wp[dd * PJ_SP + q];
        acc[j] = fmaf(xv.x, wv.x, acc[j]);
        acc[j] = fmaf(xv.y, wv.y, acc[j]);
        acc[j] = fmaf(xv.z, wv.z, acc[j]);
        acc[j] = fmaf(xv.w, wv.w, acc[j]);
      }
    }
  }
  #pragma unroll
  for (int j = 0; j < 5; ++j) {
    int dd = dg * 5 + j;
    if (dd < 38) xd[lr][dd < 6 ? dd : dd + 2] = acc[j];
  }
  __syncthreads();
  float4* xo = (float4*)(xdbl + (size_t)bk * L * ROWW + (size_t)l0 * ROWW);
  for (int i = threadIdx.x; i < 32 * 10; i += 256) {
    int lr2 = i / 10, q = i - lr2 * 10;
    xo[lr2 * 10 + q] = ((float4*)&xd[lr2][0])[q];
  }
}

// ---------------- chunked selective scan ------------------------------------
// One thread per channel (192 = 3 waves). Grid-limited occupancy (3 blk/CU),
// so the lever is ILP: 16-step tiles, phase 1 computes the 16 independent
// (s,u,sp,e1) tuples (u-loads + transcendental chains overlap), phase 2 runs
// the 16 recurrence steps (only serial dep = 4-cyc h-FMA), y as 4-way tree.
#define STILE 16
__global__ void __launch_bounds__(DI) k_scan(const float* __restrict__ xc_t,
    const float* __restrict__ xdbl, const float* __restrict__ dtw,
    const float* __restrict__ dtb, const float* __restrict__ A_logs,
    const float* __restrict__ Ds, float* __restrict__ y_sum) {
  __shared__ float4 rows[128 * 10];   // up to 128 rows x 40 floats (broadcast reads)
  int blk = blockIdx.x;
  int chk = blk & (NCHUNK - 1);
  int bk = blk >> 6;                  // NCHUNK == 64
  int k = bk % KDIR, b = bk / KDIR;
  int c = threadIdx.x;
  int lo = chk * LC;
  int ls = lo - HALO; if (ls < 0) ls = 0;
  int e = lo + LC;
  int nr = e - ls;
  const float4* rsrc = (const float4*)(xdbl + (size_t)bk * L * ROWW) + (size_t)ls * 10;
  for (int i = c; i < nr * 10; i += DI) rows[i] = rsrc[i];
  float wdt[RRANK];
  #pragma unroll
  for (int r = 0; r < RRANK; ++r) wdt[r] = dtw[(k * DI + c) * RRANK + r];
  float bias = dtb[k * DI + c];
  float Dv = Ds[k * DI + c];
  const float* alog = A_logs + (size_t)(k * DI + c) * NSTATE;
  bool fast = true;
  #pragma unroll
  for (int n = 0; n < NSTATE; ++n)
    fast = fast && (fabsf(__expf(alog[n]) - (float)(n + 1)) < 1e-4f);
  float h[NSTATE];
  #pragma unroll
  for (int n = 0; n < NSTATE; ++n) h[n] = 0.f;
  const float* ub = xc_t + (size_t)b * L * DI + c;
  float* yb = y_sum + (size_t)b * L * DI + c;
  __syncthreads();

  if (fast) {  // A[n] == -(n+1): dA[n] = e1^(n+1), log-depth powers
    for (int l0 = ls; l0 < e; l0 += STILE) {
      // ---- phase 1: 16 independent (s, u, sp, e1) tuples ----
      float spv[STILE], uv[STILE], e1v[STILE];
      int sv[STILE];
      #pragma unroll
      for (int j = 0; j < STILE; ++j) {
        int l = l0 + j;
        int s = map_s(k, l);
        sv[j] = s;
        uv[j] = ub[(size_t)s * DI];
        const float4* rp = &rows[(l - ls) * 10];
        float4 r0 = rp[0], r1 = rp[1];
        float dtv = bias;
        dtv = fmaf(r0.x, wdt[0], dtv); dtv = fmaf(r0.y, wdt[1], dtv);
        dtv = fmaf(r0.z, wdt[2], dtv); dtv = fmaf(r0.w, wdt[3], dtv);
        dtv = fmaf(r1.x, wdt[4], dtv); dtv = fmaf(r1.y, wdt[5], dtv);
        float sp = fmaxf(dtv, 0.f) + __logf(1.f + __expf(-fabsf(dtv)));
        spv[j] = sp;
        e1v[j] = __expf(-sp);
      }
      // ---- phase 2: 16 recurrence steps ----
      bool emit = (l0 >= lo);
      #pragma unroll
      for (int j = 0; j < STILE; ++j) {
        const float4* rp = &rows[(l0 + j - ls) * 10];
        float4 B0 = rp[2], B1 = rp[3], B2 = rp[4], B3 = rp[5];
        float4 C0 = rp[6], C1 = rp[7], C2 = rp[8], C3 = rp[9];
        float e1 = e1v[j];
        float dtu = spv[j] * uv[j];
        float p2 = e1 * e1, p3 = p2 * e1, p4 = p2 * p2;
        float d4 = p4 * e1, d5 = p4 * p2, d6 = p4 * p3, p8 = p4 * p4;
        float d8 = p8 * e1, d9 = p8 * p2, d10 = p8 * p3, d11 = p8 * p4;
        float d12 = p8 * d4, d13 = p8 * d5, d14 = p8 * d6, d15 = p8 * p8;
        float y0 = 0.f, y1 = 0.f, y2 = 0.f, y3 = 0.f;
        h[0]  = fmaf(e1,  h[0],  dtu * B0.x); y0 = fmaf(h[0],  C0.x, y0);
        h[1]  = fmaf(p2,  h[1],  dtu * B0.y); y1 = fmaf(h[1],  C0.y, y1);
        h[2]  = fmaf(p3,  h[2],  dtu * B0.z); y2 = fmaf(h[2],  C0.z, y2);
        h[3]  = fmaf(p4,  h[3],  dtu * B0.w); y3 = fmaf(h[3],  C0.w, y3);
        h[4]  = fmaf(d4,  h[4],  dtu * B1.x); y0 = fmaf(h[4],  C1.x, y0);
        h[5]  = fmaf(d5,  h[5],  dtu * B1.y); y1 = fmaf(h[5],  C1.y, y1);
        h[6]  = fmaf(d6,  h[6],  dtu * B1.z); y2 = fmaf(h[6],  C1.z, y2);
        h[7]  = fmaf(p8,  h[7],  dtu * B1.w); y3 = fmaf(h[7],  C1.w, y3);
        h[8]  = fmaf(d8,  h[8],  dtu * B2.x); y0 = fmaf(h[8],  C2.x, y0);
        h[9]  = fmaf(d9,  h[9],  dtu * B2.y); y1 = fmaf(h[9],  C2.y, y1);
        h[10] = fmaf(d10, h[10], dtu * B2.z); y2 = fmaf(h[10], C2.z, y2);
        h[11] = fmaf(d11, h[11], dtu * B2.w); y3 = fmaf(h[11], C2.w, y3);
        h[12] = fmaf(d12, h[12], dtu * B3.x); y0 = fmaf(h[12], C3.x, y0);
        h[13] = fmaf(d13, h[13], dtu * B3.y); y1 = fmaf(h[13], C3.y, y1);
        h[14] = fmaf(d14, h[14], dtu * B3.z); y2 = fmaf(h[14], C3.z, y2);
        h[15] = fmaf(d15, h[15], dtu * B3.w); y3 = fmaf(h[15], C3.w, y3);
        float y = (y0 + y1) + (y2 + y3);
        if (emit) atomicAdd(yb + (size_t)sv[j] * DI, fmaf(Dv, uv[j], y));
      }
    }
  } else {     // generic fallback
    for (int l = ls; l < e; ++l) {
      const float4* rp = &rows[(l - ls) * 10];
      const float* rf = (const float*)rp;
      float dtv = bias;
      #pragma unroll
      for (int r = 0; r < RRANK; ++r) dtv = fmaf(rf[r], wdt[r], dtv);
      float sp = fmaxf(dtv, 0.f) + __logf(1.f + __expf(-fabsf(dtv)));
      int s = map_s(k, l);
      float u = ub[(size_t)s * DI];
      float dtu = sp * u;
      float y = 0.f;
      #pragma unroll
      for (int n = 0; n < NSTATE; ++n) {
        float dA = __expf(sp * (-__expf(alog[n])));
        h[n] = fmaf(dA, h[n], dtu * rf[8 + n]);
        y = fmaf(h[n], rf[24 + n], y);
      }
      if (l >= lo) atomicAdd(yb + (size_t)s * DI, fmaf(Dv, u, y));
    }
  }
}

// ---------------- LN -> gate -> W_out ---------------------------------------
#define FN_SP 49
__global__ __launch_bounds__(256) void k_final(const float* __restrict__ y_sum,
    const float* __restrict__ zb, const float* __restrict__ lnw,
    const float* __restrict__ lnb, const float* __restrict__ W_out,
    float* __restrict__ out) {
  __shared__ float4 ys4[16 * FN_SP];
  float* ys = (float*)ys4;
  int p0 = blockIdx.x << 4;
  int t = threadIdx.x;
  const float4* yg = (const float4*)(y_sum + (size_t)p0 * DI);
  for (int i = t; i < 16 * 48; i += 256) {
    int r = i / 48, q = i - r * 48;
    ys4[r * FN_SP + q] = yg[i];
  }
  __syncthreads();
  {
    int r = t >> 4, lg = t & 15;
    float v[12], s1 = 0.f, s2 = 0.f;
    #pragma unroll
    for (int j2 = 0; j2 < 12; ++j2) {
      float vv = ys[r * (FN_SP * 4) + lg + 16 * j2];
      v[j2] = vv; s1 += vv; s2 += vv * vv;
    }
    #pragma unroll
    for (int m = 1; m < 16; m <<= 1) {
      s1 += __shfl_xor(s1, m, 64);
      s2 += __shfl_xor(s2, m, 64);
    }
    float mu = s1 * (1.f / DI);
    float var = s2 * (1.f / DI) - mu * mu;
    float rs = rsqrtf(var + 1e-5f);
    #pragma unroll
    for (int j2 = 0; j2 < 12; ++j2) {
      int cc = lg + 16 * j2;
      float g = zb[(size_t)(p0 + r) * DI + cc];
      float yl = (v[j2] - mu) * rs * lnw[cc] + lnb[cc];
      ys[r * (FN_SP * 4) + cc] = yl * (g / (1.f + __expf(-g)));
    }
  }
  __syncthreads();
  int oc = t % 96, pg = t / 96;       // pg in {0,1,2}; pg==2 idle
  if (pg < 2) {
    const float4* wg4 = (const float4*)W_out;
    float acc[8];
    #pragma unroll
    for (int j = 0; j < 8; ++j) acc[j] = 0.f;
    for (int q = 0; q < 48; ++q) {
      float4 wv = wg4[oc * 48 + q];
      #pragma unroll
      for (int pp = 0; pp < 8; ++pp) {
        float4 yv = ys4[(pg * 8 + pp) * FN_SP + q];
        acc[pp] = fmaf(yv.x, wv.x, acc[pp]);
        acc[pp] = fmaf(yv.y, wv.y, acc[pp]);
        acc[pp] = fmaf(yv.z, wv.z, acc[pp]);
        acc[pp] = fmaf(yv.w, wv.w, acc[pp]);
      }
    }
    #pragma unroll
    for (int pp = 0; pp < 8; ++pp)
      out[(size_t)(p0 + pg * 8 + pp) * DM + oc] = acc[pp];
  }
}

extern "C" void kernel_launch(void* const* d_in, const int* in_sizes, int n_in,
                              void* d_out, int out_size, void* d_ws, size_t ws_size,
                              hipStream_t stream) {
  const float* x        = (const float*)d_in[0];
  const float* W_in     = (const float*)d_in[1];
  const float* conv_w   = (const float*)d_in[2];
  const float* conv_b   = (const float*)d_in[3];
  const float* x_proj_w = (const float*)d_in[4];
  const float* dt_proj_w= (const float*)d_in[5];
  const float* dt_proj_b= (const float*)d_in[6];
  const float* A_logs   = (const float*)d_in[7];
  const float* Ds       = (const float*)d_in[8];
  const float* ln_w     = (const float*)d_in[9];
  const float* ln_b     = (const float*)d_in[10];
  const float* W_out    = (const float*)d_in[11];
  float* out = (float*)d_out;

  float* ws   = (float*)d_ws;
  float* regA = ws;                                    // xe_c, later ysum (B*DI*L)
  float* zb   = regA + (size_t)BATCH * DI * L;
  float* xc_c = zb   + (size_t)BATCH * L * DI;
  float* xc_t = xc_c + (size_t)BATCH * L * DI;
  float* xdbl = xc_t + (size_t)BATCH * L * DI;         // B*K*L*ROWW

  k_xz  <<<BATCH * 64 * 4, 256, 0, stream>>>(x, W_in, regA, zb);
  k_conv<<<BATCH * DI,     256, 0, stream>>>(regA, conv_w, conv_b, xc_c);
  k_tr  <<<BATCH * 6 * 128, 256, 0, stream>>>(xc_c, xc_t);
  hipMemsetAsync(regA, 0, (size_t)BATCH * L * DI * sizeof(float), stream);  // ysum
  k_proj<<<BATCH * KDIR * 128, 256, 0, stream>>>(xc_t, x_proj_w, xdbl);
  k_scan<<<BATCH * KDIR * NCHUNK, DI, 0, stream>>>(xc_t, xdbl, dt_proj_w, dt_proj_b,
                                                   A_logs, Ds, regA);
  k_final<<<BATCH * L / 16, 256, 0, stream>>>(regA, zb, ln_w, ln_b, W_out, out);
}